// Round 8
// baseline (1048.129 us; speedup 1.0000x reference)
//
#include <hip/hip_runtime.h>

#define HID   24
#define T_LEN 4096
#define BATCH 1024
#define NB    2                  // batches per wave (one per 32-lane half)
#define TPB   64                 // ONE wave per block; no __syncthreads anywhere
#define NQ    1025               // quad groups: 4100 iterations >= T_LEN+2

typedef __attribute__((ext_vector_type(2))) _Float16 h2v;
typedef __attribute__((ext_vector_type(4))) int      int4v;

__device__ __forceinline__ float dot2f(int p, int w, float acc) {
#if __has_builtin(__builtin_amdgcn_fdot2)
    return __builtin_amdgcn_fdot2(__builtin_bit_cast(h2v, p),
                                  __builtin_bit_cast(h2v, w), acc, false);
#else
    h2v a = __builtin_bit_cast(h2v, p), b = __builtin_bit_cast(h2v, w);
    acc = fmaf((float)a.x, (float)b.x, acc);
    return fmaf((float)a.y, (float)b.y, acc);
#endif
}

__device__ __forceinline__ float dot4(const float4 a, const float4 b, float acc) {
    acc = fmaf(a.x, b.x, acc);
    acc = fmaf(a.y, b.y, acc);
    acc = fmaf(a.z, b.z, acc);
    acc = fmaf(a.w, b.w, acc);
    return acc;
}

// pack two f32 -> packed f16 pair dword
#define PKF(A_, B_)                                                                 \
    (((int)__builtin_bit_cast(unsigned short, (_Float16)(B_)) << 16) |              \
     (int)__builtin_bit_cast(unsigned short, (_Float16)(A_)))

__global__ __launch_bounds__(TPB, 1) void rnn_wave_kernel(
    const float* __restrict__ x,     // [B, T]
    const float* __restrict__ h_in,  // [3, B, 24]
    const float* __restrict__ Wih0, const float* __restrict__ bih0,
    const float* __restrict__ Whh0, const float* __restrict__ bhh0,
    const float* __restrict__ Wih1, const float* __restrict__ bih1,
    const float* __restrict__ Whh1, const float* __restrict__ bhh1,
    const float* __restrict__ Wih2, const float* __restrict__ bih2,
    const float* __restrict__ Whh2, const float* __restrict__ bhh2,
    const float* __restrict__ W1,   const float* __restrict__ b1,
    const float* __restrict__ W2,   const float* __restrict__ b2,
    float* __restrict__ out)         // [1024 (y)] ++ [3*1024*24 (h_final)]
{
    // one 48B packed-f16 row per layer per batch; single-buffered (reads precede writes)
    __shared__ __align__(16) _Float16 rows[3][NB][HID];
    __shared__ float h2f[NB][HID];
    __shared__ float mbuf[NB][HID];

    const int tid  = threadIdx.x;
    const int bl   = tid >> 5;        // batch half
    const int jj   = tid & 31;
    const bool act = (jj < HID);
    const int j    = act ? jj : 0;    // clamped for safe addressing
    const int bg   = blockIdx.x * NB + bl;

    // ---- all three layers' weights in named packed-f16 registers ----
    int4v w0hA, w0hB, w0hC;                         // l0 own-h row
    int4v w1iA, w1iB, w1iC, w1hA, w1hB, w1hC;       // l1 inp + own
    int4v w2iA, w2iB, w2iC, w2hA, w2hB, w2hC;       // l2 inp + own
    float wx0, bias0, bias1, bias2;

#define MK3(ROW, DA, DB, DC) do {                                                   \
        DA = (int4v){PKF((ROW)[0], (ROW)[1]),  PKF((ROW)[2], (ROW)[3]),             \
                     PKF((ROW)[4], (ROW)[5]),  PKF((ROW)[6], (ROW)[7])};            \
        DB = (int4v){PKF((ROW)[8], (ROW)[9]),  PKF((ROW)[10], (ROW)[11]),           \
                     PKF((ROW)[12], (ROW)[13]), PKF((ROW)[14], (ROW)[15])};         \
        DC = (int4v){PKF((ROW)[16], (ROW)[17]), PKF((ROW)[18], (ROW)[19]),          \
                     PKF((ROW)[20], (ROW)[21]), PKF((ROW)[22], (ROW)[23])};         \
    } while (0)

    MK3(Whh0 + j * HID, w0hA, w0hB, w0hC);
    MK3(Wih1 + j * HID, w1iA, w1iB, w1iC);
    MK3(Whh1 + j * HID, w1hA, w1hB, w1hC);
    MK3(Wih2 + j * HID, w2iA, w2iB, w2iC);
    MK3(Whh2 + j * HID, w2hA, w2hB, w2hC);
#undef MK3
    wx0   = Wih0[j];
    bias0 = bih0[j] + bhh0[j];
    bias1 = bih1[j] + bhh1[j];
    bias2 = bih2[j] + bhh2[j];

    // ---- initial state ----
    float cur0 = h_in[(0 * BATCH + bg) * HID + j];
    float cur1 = h_in[(1 * BATCH + bg) * HID + j];
    float cur2 = h_in[(2 * BATCH + bg) * HID + j];
    if (act) {
        rows[0][bl][j] = (_Float16)cur0;
        rows[1][bl][j] = (_Float16)cur1;
        rows[2][bl][j] = (_Float16)cur2;
    }
    // same wave -> DS ordering suffices; no barrier

    const float* xrow = x + (size_t)bg * T_LEN;
    float4 xqA = *(const float4*)xrow;   // current quad
    float4 xqB;

#define DOT12(V0_, V1_, V2_, W0_, W1_, W2_)                                         \
    a0 = dot2f(V0_.x, W0_.x, a0); a1 = dot2f(V0_.y, W0_.y, a1);                     \
    a2 = dot2f(V0_.z, W0_.z, a2); a3 = dot2f(V0_.w, W0_.w, a3);                     \
    a0 = dot2f(V1_.x, W1_.x, a0); a1 = dot2f(V1_.y, W1_.y, a1);                     \
    a2 = dot2f(V1_.z, W1_.z, a2); a3 = dot2f(V1_.w, W1_.w, a3);                     \
    a0 = dot2f(V2_.x, W2_.x, a0); a1 = dot2f(V2_.y, W2_.y, a1);                     \
    a2 = dot2f(V2_.z, W2_.z, a2); a3 = dot2f(V2_.w, W2_.w, a3);

    // ---- barrier-free 3-layer software pipeline: iter u -> l0(u), l1(u-1), l2(u-2) ----
    for (int q = 0; q < NQ; ++q) {
        const int u0 = q * 4;
        // prefetch next x quad (clamped; unused values guarded out)
        const int nxt = (u0 + 4 <= T_LEN - 4) ? (u0 + 4) : (T_LEN - 4);
        xqB = *(const float4*)(xrow + nxt);

        #pragma unroll
        for (int s = 0; s < 4; ++s) {
            const int u = u0 + s;
            const float xv = (s == 0) ? xqA.x : (s == 1) ? xqA.y
                           : (s == 2) ? xqA.z : xqA.w;

            // read all three rows first (each feeds two consumers)
            const int4v* r0 = (const int4v*)&rows[0][bl][0];
            const int4v R00 = r0[0], R01 = r0[1], R02 = r0[2];
            const int4v* r1 = (const int4v*)&rows[1][bl][0];
            const int4v R10 = r1[0], R11 = r1[1], R12 = r1[2];
            const int4v* r2 = (const int4v*)&rows[2][bl][0];
            const int4v R20 = r2[0], R21 = r2[1], R22 = r2[2];

            float a0, a1, a2, a3;
            // layer 0: h0(u) = relu(wx*x(u) + Whh0 . h0(u-1) + b)
            a0 = fmaf(wx0, xv, bias0); a1 = 0.f; a2 = 0.f; a3 = 0.f;
            DOT12(R00, R01, R02, w0hA, w0hB, w0hC);
            const float v0 = fmaxf((a0 + a1) + (a2 + a3), 0.f);
            // layer 1: h1(u-1) = relu(Wih1 . h0(u-1) + Whh1 . h1(u-2) + b)
            a0 = bias1; a1 = 0.f; a2 = 0.f; a3 = 0.f;
            DOT12(R00, R01, R02, w1iA, w1iB, w1iC);
            DOT12(R10, R11, R12, w1hA, w1hB, w1hC);
            const float v1 = fmaxf((a0 + a1) + (a2 + a3), 0.f);
            // layer 2: h2(u-2) = relu(Wih2 . h1(u-2) + Whh2 . h2(u-3) + b)
            a0 = bias2; a1 = 0.f; a2 = 0.f; a3 = 0.f;
            DOT12(R10, R11, R12, w2iA, w2iB, w2iC);
            DOT12(R20, R21, R22, w2hA, w2hB, w2hC);
            const float v2 = fmaxf((a0 + a1) + (a2 + a3), 0.f);

            // latch only while active (u wave-uniform -> scalar branches)
            cur0 = (u < T_LEN) ? v0 : cur0;
            cur1 = (u >= 1 && u <= T_LEN) ? v1 : cur1;
            cur2 = (u >= 2 && u <= T_LEN + 1) ? v2 : cur2;

            // publish (reads above happen before these writes, program order)
            if (act) {
                rows[0][bl][j] = (_Float16)cur0;
                rows[1][bl][j] = (_Float16)cur1;
                rows[2][bl][j] = (_Float16)cur2;
            }
        }
        xqA = xqB;
    }
#undef DOT12

    // ---- h_final from f32 running values ----
    if (act) {
        out[BATCH + (size_t)(0 * BATCH + bg) * HID + j] = cur0;
        out[BATCH + (size_t)(1 * BATCH + bg) * HID + j] = cur1;
        out[BATCH + (size_t)(2 * BATCH + bg) * HID + j] = cur2;
        h2f[bl][j] = cur2;
    }
    // same wave -> ordered
    if (act) {
        const float4* w1r = (const float4*)(W1 + j * HID);
        const float4* hv  = (const float4*)&h2f[bl][0];
        float a = b1[j];
        a = dot4(w1r[0], hv[0], a); a = dot4(w1r[1], hv[1], a);
        a = dot4(w1r[2], hv[2], a); a = dot4(w1r[3], hv[3], a);
        a = dot4(w1r[4], hv[4], a); a = dot4(w1r[5], hv[5], a);
        mbuf[bl][j] = fmaxf(a, 0.f);
    }
    if (jj == 0) {
        float a = b2[0];
        #pragma unroll
        for (int k = 0; k < HID; ++k) a = fmaf(W2[k], mbuf[bl][k], a);
        out[bg] = fmaxf(a, 0.f);
    }
}

extern "C" void kernel_launch(void* const* d_in, const int* in_sizes, int n_in,
                              void* d_out, int out_size, void* d_ws, size_t ws_size,
                              hipStream_t stream) {
    const float* x    = (const float*)d_in[0];
    const float* h_in = (const float*)d_in[1];
    const float* Wih0 = (const float*)d_in[2];
    const float* bih0 = (const float*)d_in[3];
    const float* Whh0 = (const float*)d_in[4];
    const float* bhh0 = (const float*)d_in[5];
    const float* Wih1 = (const float*)d_in[6];
    const float* bih1 = (const float*)d_in[7];
    const float* Whh1 = (const float*)d_in[8];
    const float* bhh1 = (const float*)d_in[9];
    const float* Wih2 = (const float*)d_in[10];
    const float* bih2 = (const float*)d_in[11];
    const float* Whh2 = (const float*)d_in[12];
    const float* bhh2 = (const float*)d_in[13];
    const float* W1   = (const float*)d_in[14];
    const float* b1   = (const float*)d_in[15];
    const float* W2   = (const float*)d_in[16];
    const float* b2   = (const float*)d_in[17];
    float* out = (float*)d_out;

    dim3 grid(BATCH / NB);   // 512 single-wave blocks
    dim3 block(TPB);
    hipLaunchKernelGGL(rnn_wave_kernel, grid, block, 0, stream,
                       x, h_in, Wih0, bih0, Whh0, bhh0,
                       Wih1, bih1, Whh1, bhh1, Wih2, bih2, Whh2, bhh2,
                       W1, b1, W2, b2, out);
}